// Round 4
// baseline (154.216 us; speedup 1.0000x reference)
//
#include <hip/hip_runtime.h>

// LengthRegulator: x [B,T,D] f32, dur [B,T] int -> out [B,M,D] f32
// M = out_size / (B*D). Semantics (== jnp.searchsorted(cumsum, m, 'right') clip T-1):
//   token j owns output rows [c[j-1], c[j]) with c = cumsum(max(dur,0));
//   zero-duration tokens own nothing; rows [total, M) get x row T-1.
// Single fused kernel: every block re-derives its batch's scan (wave-0 scan,
// ~200ns, 2KB L2-hit loads), then expands its 4 tokens / tail slice.

typedef float f32x4 __attribute__((ext_vector_type(4)));   // nontemporal-friendly

#define B_BATCH 32
#define T_TOK   512
#define D_DIM   512
#define DQ      (D_DIM / 4)   // 128 f32x4 per feature row
#define TPB     4             // tokens per 512-thread block
#define MAINB   (T_TOK / TPB) // 128 main blocks per batch
#define TAILB   32            // tail-fill blocks per batch

__global__ __launch_bounds__(TPB * DQ)
void lr_fused(const f32x4* __restrict__ x,
              const int* __restrict__ dur,
              f32x4* __restrict__ out, int M) {
    __shared__ int s[T_TOK + 1];   // exclusive starts; s[T_TOK] = total
    const int b = blockIdx.y;

    // ---- wave-0 scan of the batch's 512 durations (8 tokens/lane) ----
    if (threadIdx.x < 64) {
        const int l = threadIdx.x;
        const int4* drow = (const int4*)(dur + b * T_TOK);
        int4 a0 = drow[l * 2];
        int4 a1 = drow[l * 2 + 1];
        int v[8] = {a0.x, a0.y, a0.z, a0.w, a1.x, a1.y, a1.z, a1.w};
        int p[8], run = 0;
        #pragma unroll
        for (int k = 0; k < 8; ++k) {
            int d = v[k] > 0 ? v[k] : 0;
            p[k] = run;            // local exclusive prefix
            run += d;
        }
        int inc = run;             // wave inclusive scan of per-lane sums
        #pragma unroll
        for (int off = 1; off < 64; off <<= 1) {
            int u = __shfl_up(inc, off);
            if (l >= off) inc += u;
        }
        const int base = inc - run;  // exclusive base for this lane
        #pragma unroll
        for (int k = 0; k < 8; ++k) s[l * 8 + k] = base + p[k];
        if (l == 63) s[T_TOK] = inc; // row total
    }
    __syncthreads();

    const int q   = threadIdx.x & (DQ - 1);  // feature-quad 0..127
    const int sub = threadIdx.x >> 7;        // row-group 0..3

    if (blockIdx.x < MAINB) {
        const int t  = blockIdx.x * TPB + sub;
        const int st = s[t];
        const int en = s[t + 1];
        if (en <= st) return;
        const f32x4 v = x[((size_t)b * T_TOK + t) * DQ + q];
        f32x4* o = out + ((size_t)b * M + st) * DQ + q;
        for (int r = st; r < en; ++r, o += DQ)
            __builtin_nontemporal_store(v, o);
    } else {
        const int tot = s[T_TOK];
        if (tot >= M) return;
        const f32x4 v = x[((size_t)b * T_TOK + (T_TOK - 1)) * DQ + q];
        const int j = blockIdx.x - MAINB;    // 0..TAILB-1
        for (int r = tot + j * TPB + sub; r < M; r += TAILB * TPB)
            __builtin_nontemporal_store(v, out + ((size_t)b * M + r) * DQ + q);
    }
}

extern "C" void kernel_launch(void* const* d_in, const int* in_sizes, int n_in,
                              void* d_out, int out_size, void* d_ws, size_t ws_size,
                              hipStream_t stream) {
    const float* x = (const float*)d_in[0];
    const int* dur = (const int*)d_in[1];
    float* out     = (float*)d_out;

    const int M = out_size / (B_BATCH * D_DIM);

    dim3 grid(MAINB + TAILB, B_BATCH);
    lr_fused<<<grid, TPB * DQ, 0, stream>>>((const f32x4*)x, dur,
                                            (f32x4*)out, M);
}